// Round 3
// baseline (360.947 us; speedup 1.0000x reference)
//
#include <hip/hip_runtime.h>

#define NTOK 196
#define QPAD 208
#define KP 208
#define PSTR 232

typedef __attribute__((ext_vector_type(8))) short short8;
typedef __attribute__((ext_vector_type(4))) float float4_t;

__device__ __forceinline__ short f2bf(float f) {
  unsigned u = __float_as_uint(f);
  u = (u + 0x7fffu + ((u >> 16) & 1u)) >> 16;
  return (short)u;
}
__device__ __forceinline__ float bf2f(short s) {
  return __uint_as_float(((unsigned)(unsigned short)s) << 16);
}

// ---------------- fallback: signal insufficient workspace ----------------
__global__ __launch_bounds__(256) void fill_kernel(float* __restrict__ out,
                                                   int n) {
  int i = blockIdx.x * 256 + threadIdx.x;
  if (i < n) out[i] = 1000.0f;
}

// ------------- weight transpose+cvt: out_bf16[C][R] = in_f32[R][C] -----------
__global__ __launch_bounds__(256) void transpose_kernel(
    const float* __restrict__ in, short* __restrict__ out, int R, int C) {
  __shared__ float tile[64][65];
  int c0 = blockIdx.x * 64, r0 = blockIdx.y * 64;
  int tc = threadIdx.x & 63, tr = threadIdx.x >> 6;
#pragma unroll
  for (int s = 0; s < 16; s++) {
    int r = s * 4 + tr;
    tile[r][tc] = in[(r0 + r) * C + c0 + tc];
  }
  __syncthreads();
#pragma unroll
  for (int s = 0; s < 16; s++) {
    int i = s * 4 + tr;
    out[(c0 + i) * R + r0 + tc] = f2bf(tile[tc][i]);
  }
}

// ---------------- bias precompute: bias[h][q<208][k<208] fp32 ----------------
__global__ __launch_bounds__(256) void bias_kernel(
    const float* __restrict__ table, const int* __restrict__ rpi,
    float* __restrict__ bias) {
  int idx = blockIdx.x * 256 + threadIdx.x;
  if (idx >= 16 * QPAD * KP) return;
  int h = idx / (QPAD * KP);
  int rem = idx % (QPAD * KP);
  int q = rem / KP, k = rem % KP;
  float v = 0.f;
  if (q < NTOK && k < NTOK) v = table[rpi[q * NTOK + k] * 16 + h];
  bias[idx] = v;
}

// ---------------- fused QKV-GEMM + attention, one block per (b,h) ----------
__global__ __launch_bounds__(256, 2) void fused_attn(
    const float* __restrict__ x, const short* __restrict__ wt1,
    const float* __restrict__ bias, short* __restrict__ aout) {
  // R1: GEMM x-staging As[224][40], later P[64][232]
  // R2: GEMM w-staging Bs[96][40], later vT[32][232]
  __shared__ __align__(16) short R1[64 * PSTR];
  __shared__ __align__(16) short R2[32 * PSTR];
  __shared__ __align__(16) short Qs[224][40];
  __shared__ __align__(16) short Ks[224][40];
  short(*As)[40] = (short(*)[40])R1;
  short(*P)[PSTR] = (short(*)[PSTR])R1;
  short(*Bs)[40] = (short(*)[40])R2;
  short(*vTs)[PSTR] = (short(*)[PSTR])R2;

  int bh = blockIdx.x, b = bh >> 4, h = bh & 15;
  int tid = threadIdx.x, wave = tid >> 6, lane = tid & 63;
  int quad = lane >> 4, l16 = lane & 15;
  int base_row = b * NTOK;

  float4_t z4 = {0.f, 0.f, 0.f, 0.f};
  float4_t acc[4][6];
#pragma unroll
  for (int i = 0; i < 4; i++)
#pragma unroll
    for (int n = 0; n < 6; n++) acc[i][n] = z4;

  int srow = tid >> 2, scol = (tid & 3) * 8;
  // -------- QKV GEMM: C[224][96] = x[224][512] * w3[96][512]^T --------
  for (int k0 = 0; k0 < 512; k0 += 32) {
#pragma unroll
    for (int i = 0; i < 4; i++) {
      int r = srow + i * 64;
      if (r < 224) {
        int gr = base_row + r;
        if (gr > 25087) gr = 25087;  // clamp: last batch pad rows
        const float* xp = &x[gr * 512 + k0 + scol];
        short8 v;
#pragma unroll
        for (int j = 0; j < 8; j++) v[j] = f2bf(xp[j]);
        *(short8*)&As[r][scol] = v;
      }
    }
#pragma unroll
    for (int i = 0; i < 2; i++) {
      int r = srow + i * 64;
      if (r < 96) {
        int sec = r >> 5, r32 = r & 31;
        *(short8*)&Bs[r][scol] =
            *(const short8*)&wt1[(sec * 512 + h * 32 + r32) * 512 + k0 + scol];
      }
    }
    __syncthreads();
    short8 af[4], bfv[6];
#pragma unroll
    for (int i = 0; i < 4; i++) {
      int mt = (i < 3) ? (wave + 4 * i) : (12 + (wave & 1));
      af[i] = *(short8*)&As[mt * 16 + l16][quad * 8];
    }
#pragma unroll
    for (int n = 0; n < 6; n++) bfv[n] = *(short8*)&Bs[n * 16 + l16][quad * 8];
#pragma unroll
    for (int i = 0; i < 4; i++)
#pragma unroll
      for (int n = 0; n < 6; n++)
        acc[i][n] = __builtin_amdgcn_mfma_f32_16x16x32_bf16(af[i], bfv[n],
                                                            acc[i][n], 0, 0, 0);
    __syncthreads();
  }
  // -------- epilogue: scatter to Qs (scaled), Ks, vTs (transposed) --------
  const float qscale = 0.17677669529663687f;  // 32^-0.5
#pragma unroll
  for (int i = 0; i < 4; i++) {
    if (i == 3 && wave >= 2) break;
    int mt = (i < 3) ? (wave + 4 * i) : (12 + wave);
    int row0 = mt * 16 + quad * 4;
#pragma unroll
    for (int n = 0; n < 6; n++) {
      int c = n * 16 + l16;
#pragma unroll
      for (int r = 0; r < 4; r++) {
        int row = row0 + r;
        float v = acc[i][n][r];
        if (c < 32)
          Qs[row][c] = f2bf(v * qscale);
        else if (c < 64)
          Ks[row][c - 32] = f2bf(v);
        else
          vTs[c - 64][row] = f2bf(v);
      }
    }
  }
  __syncthreads();
  // -------- attention: 4 uniform iterations; wave w owns q-tiles w,w+4,w+8,
  // and wave 0 additionally tile 12 in iteration 3 ------------------------
  for (int i2 = 0; i2 < 4; i2++) {
    bool active = (i2 < 3) || (wave == 0);
    int qt = (i2 < 3) ? (wave + 4 * i2) : 12;
    int qr0 = qt * 16;
    if (active) {
      short8 qf = *(short8*)&Qs[qr0 + l16][quad * 8];
      float4_t s[13];
#pragma unroll
      for (int kt = 0; kt < 13; kt++) {
        short8 kf = *(short8*)&Ks[kt * 16 + l16][quad * 8];
        s[kt] = __builtin_amdgcn_mfma_f32_16x16x32_bf16(qf, kf, z4, 0, 0, 0);
      }
      const float* brow = bias + (h * QPAD + qr0 + quad * 4) * KP;
#pragma unroll
      for (int kt = 0; kt < 13; kt++) {
        int col = kt * 16 + l16;
#pragma unroll
        for (int r = 0; r < 4; r++) s[kt][r] += brow[r * KP + col];
      }
      if (l16 >= 4) {
#pragma unroll
        for (int r = 0; r < 4; r++) s[12][r] = -1e30f;  // mask pad keys
      }
      int prow_base = wave * 16 + quad * 4;
#pragma unroll
      for (int r = 0; r < 4; r++) {
        float m = s[0][r];
#pragma unroll
        for (int kt = 1; kt < 13; kt++) m = fmaxf(m, s[kt][r]);
        m = fmaxf(m, __shfl_xor(m, 8, 16));
        m = fmaxf(m, __shfl_xor(m, 4, 16));
        m = fmaxf(m, __shfl_xor(m, 2, 16));
        m = fmaxf(m, __shfl_xor(m, 1, 16));
        float sum = 0.f;
#pragma unroll
        for (int kt = 0; kt < 13; kt++) {
          float p = __expf(s[kt][r] - m);
          s[kt][r] = p;
          sum += p;
        }
        sum += __shfl_xor(sum, 8, 16);
        sum += __shfl_xor(sum, 4, 16);
        sum += __shfl_xor(sum, 2, 16);
        sum += __shfl_xor(sum, 1, 16);
        float inv = 1.f / sum;
        short* prow = &P[prow_base + r][0];
#pragma unroll
        for (int kt = 0; kt < 13; kt++)
          prow[kt * 16 + l16] = f2bf(s[kt][r] * inv);
        prow[208 + l16] = 0;  // zero pad cols 208..223 (224.. never read)
      }
    }
    __syncthreads();  // P writes ordered/visible before fragment reads
    if (active) {
      float4_t o0 = z4, o1 = z4;
#pragma unroll
      for (int kt = 0; kt < 7; kt++) {
        short8 pf = *(short8*)&P[wave * 16 + l16][kt * 32 + quad * 8];
        short8 vf0 = *(short8*)&vTs[l16][kt * 32 + quad * 8];
        short8 vf1 = *(short8*)&vTs[16 + l16][kt * 32 + quad * 8];
        o0 = __builtin_amdgcn_mfma_f32_16x16x32_bf16(pf, vf0, o0, 0, 0, 0);
        o1 = __builtin_amdgcn_mfma_f32_16x16x32_bf16(pf, vf1, o1, 0, 0, 0);
      }
#pragma unroll
      for (int r = 0; r < 4; r++) {
        int row = qr0 + quad * 4 + r;
        if (row < NTOK) {
          int off = (base_row + row) * 512 + h * 32;
          aout[off + l16] = f2bf(o0[r]);
          aout[off + 16 + l16] = f2bf(o1[r]);
        }
      }
    }
    __syncthreads();  // protect P slab before next iteration's overwrite
  }
}

// ------------- proj GEMM + bias: out_f32 = aout[25088,512] @ w2^T + b --------
__device__ __forceinline__ void gemm_tile(const short* __restrict__ A,
                                          const short* __restrict__ B, int K,
                                          int m0, int n0, short (*As)[72],
                                          short (*Bs)[72], float4_t acc[4][4]) {
  int tid = threadIdx.x;
  int lane = tid & 63, wave = tid >> 6;
  int quad = lane >> 4, l16 = lane & 15;
  int wm = (wave >> 1) * 64, wn = (wave & 1) * 64;
  int srow = tid >> 3, scol = (tid & 7) * 8;
  for (int k0 = 0; k0 < K; k0 += 64) {
#pragma unroll
    for (int i = 0; i < 4; i++) {
      int r = srow + i * 32;
      *(short8*)&As[r][scol] = *(const short8*)&A[(m0 + r) * K + k0 + scol];
      *(short8*)&Bs[r][scol] = *(const short8*)&B[(n0 + r) * K + k0 + scol];
    }
    __syncthreads();
#pragma unroll
    for (int ks = 0; ks < 2; ks++) {
      short8 af[4], bfr[4];
#pragma unroll
      for (int i = 0; i < 4; i++) {
        af[i] = *(short8*)&As[wm + i * 16 + l16][ks * 32 + quad * 8];
        bfr[i] = *(short8*)&Bs[wn + i * 16 + l16][ks * 32 + quad * 8];
      }
#pragma unroll
      for (int mi = 0; mi < 4; mi++)
#pragma unroll
        for (int ni = 0; ni < 4; ni++)
          acc[mi][ni] = __builtin_amdgcn_mfma_f32_16x16x32_bf16(
              af[mi], bfr[ni], acc[mi][ni], 0, 0, 0);
    }
    __syncthreads();
  }
}

__global__ __launch_bounds__(256) void proj_gemm(
    const short* __restrict__ a, const short* __restrict__ wt,
    const float* __restrict__ pb, float* __restrict__ out) {
  __shared__ __align__(16) short As[128][72];
  __shared__ __align__(16) short Bs[128][72];
  float4_t acc[4][4];
  float4_t z = {0.f, 0.f, 0.f, 0.f};
#pragma unroll
  for (int i = 0; i < 4; i++)
#pragma unroll
    for (int j = 0; j < 4; j++) acc[i][j] = z;
  int m0 = blockIdx.y * 128, n0 = blockIdx.x * 128;
  gemm_tile(a, wt, 512, m0, n0, As, Bs, acc);
  int lane = threadIdx.x & 63, wave = threadIdx.x >> 6;
  int quad = lane >> 4, l16 = lane & 15;
  int wm = (wave >> 1) * 64, wn = (wave & 1) * 64;
#pragma unroll
  for (int mi = 0; mi < 4; mi++)
#pragma unroll
    for (int ni = 0; ni < 4; ni++) {
      int colg = n0 + wn + ni * 16 + l16;
      float bv = pb[colg];
#pragma unroll
      for (int r = 0; r < 4; r++) {
        int rowg = m0 + wm + mi * 16 + quad * 4 + r;
        out[rowg * 512 + colg] = acc[mi][ni][r] + bv;
      }
    }
}

extern "C" void kernel_launch(void* const* d_in, const int* in_sizes, int n_in,
                              void* d_out, int out_size, void* d_ws,
                              size_t ws_size, hipStream_t stream) {
  const float* x = (const float*)d_in[0];       // [25088,512] fp32
  const float* qkv_w = (const float*)d_in[1];   // [512,1536] fp32
  const float* table = (const float*)d_in[2];   // [729,16] fp32
  const float* proj_w = (const float*)d_in[3];  // [512,512] fp32
  const float* proj_b = (const float*)d_in[4];  // [512] fp32
  const int* rpi = (const int*)d_in[5];         // [196,196] int32
  float* out = (float*)d_out;

  // workspace layout (30,556,160 bytes total — proven to fit in round 2)
  const size_t NEEDED = 30556160;
  if (ws_size < NEEDED) {  // deterministic diagnostic fallback
    fill_kernel<<<(out_size + 255) / 256, 256, 0, stream>>>(out, out_size);
    return;
  }
  char* w = (char*)d_ws;
  short* wt1 = (short*)(w);              // 1536*512*2   = 1,572,864
  short* wt2 = (short*)(w + 1572864);    // 512*512*2    =   524,288
  float* bias = (float*)(w + 2097152);   // 16*208*208*4 = 2,768,896
  short* aout = (short*)(w + 4866048);   // 25088*512*2  = 25,690,112

  transpose_kernel<<<dim3(24, 8), 256, 0, stream>>>(qkv_w, wt1, 512, 1536);
  transpose_kernel<<<dim3(8, 8), 256, 0, stream>>>(proj_w, wt2, 512, 512);
  bias_kernel<<<(16 * QPAD * KP + 255) / 256, 256, 0, stream>>>(table, rpi,
                                                                bias);
  fused_attn<<<2048, 256, 0, stream>>>(x, wt1, bias, aout);
  proj_gemm<<<dim3(4, 196), 256, 0, stream>>>(aout, wt2, proj_b, out);
}

// Round 4
// 321.433 us; speedup vs baseline: 1.1229x; 1.1229x over previous
//
#include <hip/hip_runtime.h>

#define NTOK 196
#define QPAD 208
#define KP 208
#define PSTR 232

typedef __attribute__((ext_vector_type(8))) short short8;
typedef __attribute__((ext_vector_type(4))) float float4_t;

__device__ __forceinline__ short f2bf(float f) {
  unsigned u = __float_as_uint(f);
  u = (u + 0x7fffu + ((u >> 16) & 1u)) >> 16;
  return (short)u;
}

// ---------------- fallback: signal insufficient workspace ----------------
__global__ __launch_bounds__(256) void fill_kernel(float* __restrict__ out,
                                                   int n) {
  int i = blockIdx.x * 256 + threadIdx.x;
  if (i < n) out[i] = 1000.0f;
}

// ---------------- x fp32 -> bf16, 8 elems/thread ----------------
__global__ __launch_bounds__(256) void cvt_kernel(const float* __restrict__ in,
                                                  short* __restrict__ out) {
  int i = (blockIdx.x * 256 + threadIdx.x) * 8;  // total = 25088*512
  float4_t a = *(const float4_t*)&in[i];
  float4_t b = *(const float4_t*)&in[i + 4];
  short8 v;
  v[0] = f2bf(a[0]); v[1] = f2bf(a[1]); v[2] = f2bf(a[2]); v[3] = f2bf(a[3]);
  v[4] = f2bf(b[0]); v[5] = f2bf(b[1]); v[6] = f2bf(b[2]); v[7] = f2bf(b[3]);
  *(short8*)&out[i] = v;
}

// ------------- weight transpose+cvt: out_bf16[C][R] = in_f32[R][C] -----------
__global__ __launch_bounds__(256) void transpose_kernel(
    const float* __restrict__ in, short* __restrict__ out, int R, int C) {
  __shared__ float tile[64][65];
  int c0 = blockIdx.x * 64, r0 = blockIdx.y * 64;
  int tc = threadIdx.x & 63, tr = threadIdx.x >> 6;
#pragma unroll
  for (int s = 0; s < 16; s++) {
    int r = s * 4 + tr;
    tile[r][tc] = in[(r0 + r) * C + c0 + tc];
  }
  __syncthreads();
#pragma unroll
  for (int s = 0; s < 16; s++) {
    int i = s * 4 + tr;
    out[(c0 + i) * R + r0 + tc] = f2bf(tile[tc][i]);
  }
}

// ---------------- bias precompute: bias[h][q<208][k<208] fp32 ----------------
__global__ __launch_bounds__(256) void bias_kernel(
    const float* __restrict__ table, const int* __restrict__ rpi,
    float* __restrict__ bias) {
  int idx = blockIdx.x * 256 + threadIdx.x;
  if (idx >= 16 * QPAD * KP) return;
  int h = idx / (QPAD * KP);
  int rem = idx % (QPAD * KP);
  int q = rem / KP, k = rem % KP;
  float v = 0.f;
  if (q < NTOK && k < NTOK) v = table[rpi[q * NTOK + k] * 16 + h];
  bias[idx] = v;
}

// ---------------- fused QKV-GEMM + attention, one block per (b,h) ----------
__global__ __launch_bounds__(256, 2) void fused_attn(
    const short* __restrict__ xb, const short* __restrict__ wt1,
    const float* __restrict__ bias, short* __restrict__ aout) {
  // R1: GEMM x-staging As[224][40], later P[64][232]
  // R2: GEMM w-staging Bs[96][40], later vT[32][232]
  __shared__ __align__(16) short R1[64 * PSTR];
  __shared__ __align__(16) short R2[32 * PSTR];
  __shared__ __align__(16) short Qs[224][40];
  __shared__ __align__(16) short Ks[224][40];
  short(*As)[40] = (short(*)[40])R1;
  short(*P)[PSTR] = (short(*)[PSTR])R1;
  short(*Bs)[40] = (short(*)[40])R2;
  short(*vTs)[PSTR] = (short(*)[PSTR])R2;

  int bh = blockIdx.x, b = bh >> 4, h = bh & 15;
  int tid = threadIdx.x, wave = tid >> 6, lane = tid & 63;
  int quad = lane >> 4, l16 = lane & 15;
  int base_row = b * NTOK;

  float4_t z4 = {0.f, 0.f, 0.f, 0.f};
  float4_t acc[4][6];
#pragma unroll
  for (int i = 0; i < 4; i++)
#pragma unroll
    for (int n = 0; n < 6; n++) acc[i][n] = z4;

  int srow = tid >> 2, scol = (tid & 3) * 8;
  // -------- QKV GEMM: C[224][96] = x[224][512] * w3[96][512]^T --------
  for (int k0 = 0; k0 < 512; k0 += 32) {
#pragma unroll
    for (int i = 0; i < 4; i++) {
      int r = srow + i * 64;
      if (r < 224) {
        int gr = base_row + r;
        if (gr > 25087) gr = 25087;  // clamp: last batch pad rows
        *(short8*)&As[r][scol] = *(const short8*)&xb[gr * 512 + k0 + scol];
      }
    }
#pragma unroll
    for (int i = 0; i < 2; i++) {
      int r = srow + i * 64;
      if (r < 96) {
        int sec = r >> 5, r32 = r & 31;
        *(short8*)&Bs[r][scol] =
            *(const short8*)&wt1[(sec * 512 + h * 32 + r32) * 512 + k0 + scol];
      }
    }
    __syncthreads();
    short8 af[4], bfv[6];
#pragma unroll
    for (int i = 0; i < 4; i++) {
      int mt = (i < 3) ? (wave + 4 * i) : (12 + (wave & 1));
      af[i] = *(short8*)&As[mt * 16 + l16][quad * 8];
    }
#pragma unroll
    for (int n = 0; n < 6; n++) bfv[n] = *(short8*)&Bs[n * 16 + l16][quad * 8];
#pragma unroll
    for (int i = 0; i < 4; i++)
#pragma unroll
      for (int n = 0; n < 6; n++)
        acc[i][n] = __builtin_amdgcn_mfma_f32_16x16x32_bf16(af[i], bfv[n],
                                                            acc[i][n], 0, 0, 0);
    __syncthreads();
  }
  // -------- epilogue: scatter to Qs (scaled), Ks, vTs (transposed) --------
  const float qscale = 0.17677669529663687f;  // 32^-0.5
#pragma unroll
  for (int i = 0; i < 4; i++) {
    if (i == 3 && wave >= 2) break;
    int mt = (i < 3) ? (wave + 4 * i) : (12 + wave);
    int row0 = mt * 16 + quad * 4;
#pragma unroll
    for (int n = 0; n < 6; n++) {
      int c = n * 16 + l16;
#pragma unroll
      for (int r = 0; r < 4; r++) {
        int row = row0 + r;
        float v = acc[i][n][r];
        if (c < 32)
          Qs[row][c] = f2bf(v * qscale);
        else if (c < 64)
          Ks[row][c - 32] = f2bf(v);
        else
          vTs[c - 64][row] = f2bf(v);
      }
    }
  }
  __syncthreads();
  // -------- attention: 4 uniform iterations; wave w owns q-tiles w,w+4,w+8,
  // and wave 0 additionally tile 12 in iteration 3 ------------------------
  for (int i2 = 0; i2 < 4; i2++) {
    bool active = (i2 < 3) || (wave == 0);
    int qt = (i2 < 3) ? (wave + 4 * i2) : 12;
    int qr0 = qt * 16;
    if (active) {
      short8 qf = *(short8*)&Qs[qr0 + l16][quad * 8];
      float4_t s[13];
#pragma unroll
      for (int kt = 0; kt < 13; kt++) {
        short8 kf = *(short8*)&Ks[kt * 16 + l16][quad * 8];
        s[kt] = __builtin_amdgcn_mfma_f32_16x16x32_bf16(qf, kf, z4, 0, 0, 0);
      }
      const float* brow = bias + (h * QPAD + qr0 + quad * 4) * KP;
#pragma unroll
      for (int kt = 0; kt < 13; kt++) {
        int col = kt * 16 + l16;
#pragma unroll
        for (int r = 0; r < 4; r++) s[kt][r] += brow[r * KP + col];
      }
      if (l16 >= 4) {
#pragma unroll
        for (int r = 0; r < 4; r++) s[12][r] = -1e30f;  // mask pad keys
      }
      int prow_base = wave * 16 + quad * 4;
#pragma unroll
      for (int r = 0; r < 4; r++) {
        float m = s[0][r];
#pragma unroll
        for (int kt = 1; kt < 13; kt++) m = fmaxf(m, s[kt][r]);
        m = fmaxf(m, __shfl_xor(m, 8, 16));
        m = fmaxf(m, __shfl_xor(m, 4, 16));
        m = fmaxf(m, __shfl_xor(m, 2, 16));
        m = fmaxf(m, __shfl_xor(m, 1, 16));
        float sum = 0.f;
#pragma unroll
        for (int kt = 0; kt < 13; kt++) {
          float p = __expf(s[kt][r] - m);
          s[kt][r] = p;
          sum += p;
        }
        sum += __shfl_xor(sum, 8, 16);
        sum += __shfl_xor(sum, 4, 16);
        sum += __shfl_xor(sum, 2, 16);
        sum += __shfl_xor(sum, 1, 16);
        float inv = 1.f / sum;
        short* prow = &P[prow_base + r][0];
#pragma unroll
        for (int kt = 0; kt < 13; kt++)
          prow[kt * 16 + l16] = f2bf(s[kt][r] * inv);
        prow[208 + l16] = 0;  // zero pad cols 208..223 (224.. never read)
      }
    }
    __syncthreads();  // P writes ordered/visible before fragment reads
    if (active) {
      float4_t o0 = z4, o1 = z4;
#pragma unroll
      for (int kt = 0; kt < 7; kt++) {
        short8 pf = *(short8*)&P[wave * 16 + l16][kt * 32 + quad * 8];
        short8 vf0 = *(short8*)&vTs[l16][kt * 32 + quad * 8];
        short8 vf1 = *(short8*)&vTs[16 + l16][kt * 32 + quad * 8];
        o0 = __builtin_amdgcn_mfma_f32_16x16x32_bf16(pf, vf0, o0, 0, 0, 0);
        o1 = __builtin_amdgcn_mfma_f32_16x16x32_bf16(pf, vf1, o1, 0, 0, 0);
      }
#pragma unroll
      for (int r = 0; r < 4; r++) {
        int row = qr0 + quad * 4 + r;
        if (row < NTOK) {
          int off = (base_row + row) * 512 + h * 32;
          aout[off + l16] = f2bf(o0[r]);
          aout[off + 16 + l16] = f2bf(o1[r]);
        }
      }
    }
    __syncthreads();  // protect P slab before next iteration's overwrite
  }
}

// ------------- proj GEMM + bias: out_f32 = aout[25088,512] @ w2^T + b --------
__device__ __forceinline__ void gemm_tile(const short* __restrict__ A,
                                          const short* __restrict__ B, int K,
                                          int m0, int n0, short (*As)[72],
                                          short (*Bs)[72], float4_t acc[4][4]) {
  int tid = threadIdx.x;
  int lane = tid & 63, wave = tid >> 6;
  int quad = lane >> 4, l16 = lane & 15;
  int wm = (wave >> 1) * 64, wn = (wave & 1) * 64;
  int srow = tid >> 3, scol = (tid & 7) * 8;
  for (int k0 = 0; k0 < K; k0 += 64) {
#pragma unroll
    for (int i = 0; i < 4; i++) {
      int r = srow + i * 32;
      *(short8*)&As[r][scol] = *(const short8*)&A[(m0 + r) * K + k0 + scol];
      *(short8*)&Bs[r][scol] = *(const short8*)&B[(n0 + r) * K + k0 + scol];
    }
    __syncthreads();
#pragma unroll
    for (int ks = 0; ks < 2; ks++) {
      short8 af[4], bfr[4];
#pragma unroll
      for (int i = 0; i < 4; i++) {
        af[i] = *(short8*)&As[wm + i * 16 + l16][ks * 32 + quad * 8];
        bfr[i] = *(short8*)&Bs[wn + i * 16 + l16][ks * 32 + quad * 8];
      }
#pragma unroll
      for (int mi = 0; mi < 4; mi++)
#pragma unroll
        for (int ni = 0; ni < 4; ni++)
          acc[mi][ni] = __builtin_amdgcn_mfma_f32_16x16x32_bf16(
              af[mi], bfr[ni], acc[mi][ni], 0, 0, 0);
    }
    __syncthreads();
  }
}

__global__ __launch_bounds__(256) void proj_gemm(
    const short* __restrict__ a, const short* __restrict__ wt,
    const float* __restrict__ pb, float* __restrict__ out) {
  __shared__ __align__(16) short As[128][72];
  __shared__ __align__(16) short Bs[128][72];
  float4_t acc[4][4];
  float4_t z = {0.f, 0.f, 0.f, 0.f};
#pragma unroll
  for (int i = 0; i < 4; i++)
#pragma unroll
    for (int j = 0; j < 4; j++) acc[i][j] = z;
  int m0 = blockIdx.y * 128, n0 = blockIdx.x * 128;
  gemm_tile(a, wt, 512, m0, n0, As, Bs, acc);
  int lane = threadIdx.x & 63, wave = threadIdx.x >> 6;
  int quad = lane >> 4, l16 = lane & 15;
  int wm = (wave >> 1) * 64, wn = (wave & 1) * 64;
#pragma unroll
  for (int mi = 0; mi < 4; mi++)
#pragma unroll
    for (int ni = 0; ni < 4; ni++) {
      int colg = n0 + wn + ni * 16 + l16;
      float bv = pb[colg];
#pragma unroll
      for (int r = 0; r < 4; r++) {
        int rowg = m0 + wm + mi * 16 + quad * 4 + r;
        out[rowg * 512 + colg] = acc[mi][ni][r] + bv;
      }
    }
}

extern "C" void kernel_launch(void* const* d_in, const int* in_sizes, int n_in,
                              void* d_out, int out_size, void* d_ws,
                              size_t ws_size, hipStream_t stream) {
  const float* x = (const float*)d_in[0];       // [25088,512] fp32
  const float* qkv_w = (const float*)d_in[1];   // [512,1536] fp32
  const float* table = (const float*)d_in[2];   // [729,16] fp32
  const float* proj_w = (const float*)d_in[3];  // [512,512] fp32
  const float* proj_b = (const float*)d_in[4];  // [512] fp32
  const int* rpi = (const int*)d_in[5];         // [196,196] int32
  float* out = (float*)d_out;

  // workspace layout (56,246,272 bytes total)
  const size_t NEEDED = 56246272;
  if (ws_size < NEEDED) {  // deterministic diagnostic fallback (absmax ~1000)
    fill_kernel<<<(out_size + 255) / 256, 256, 0, stream>>>(out, out_size);
    return;
  }
  char* w = (char*)d_ws;
  short* wt1 = (short*)(w);              // 1536*512*2   = 1,572,864
  short* wt2 = (short*)(w + 1572864);    // 512*512*2    =   524,288
  float* bias = (float*)(w + 2097152);   // 16*208*208*4 = 2,768,896
  short* aout = (short*)(w + 4866048);   // 25088*512*2  = 25,690,112
  short* xb = (short*)(w + 30556160);    // 25088*512*2  = 25,690,112

  cvt_kernel<<<25088 * 512 / (256 * 8), 256, 0, stream>>>(x, xb);
  transpose_kernel<<<dim3(24, 8), 256, 0, stream>>>(qkv_w, wt1, 512, 1536);
  transpose_kernel<<<dim3(8, 8), 256, 0, stream>>>(proj_w, wt2, 512, 512);
  bias_kernel<<<(16 * QPAD * KP + 255) / 256, 256, 0, stream>>>(table, rpi,
                                                                bias);
  fused_attn<<<2048, 256, 0, stream>>>(xb, wt1, bias, aout);
  proj_gemm<<<dim3(4, 196), 256, 0, stream>>>(aout, wt2, proj_b, out);
}

// Round 5
// 280.196 us; speedup vs baseline: 1.2882x; 1.1472x over previous
//
#include <hip/hip_runtime.h>

#define NTOK 196
#define QPAD 208
#define KP 208
#define PSTR 232

typedef __attribute__((ext_vector_type(8))) short short8;
typedef __attribute__((ext_vector_type(4))) float float4_t;

__device__ __forceinline__ short f2bf(float f) {
  unsigned u = __float_as_uint(f);
  u = (u + 0x7fffu + ((u >> 16) & 1u)) >> 16;
  return (short)u;
}

// ---------------- fallback: signal insufficient workspace ----------------
__global__ __launch_bounds__(256) void fill_kernel(float* __restrict__ out,
                                                   int n) {
  int i = blockIdx.x * 256 + threadIdx.x;
  if (i < n) out[i] = 1000.0f;
}

// ---------------- x fp32 -> bf16, 8 elems/thread ----------------
__global__ __launch_bounds__(256) void cvt_kernel(const float* __restrict__ in,
                                                  short* __restrict__ out) {
  int i = (blockIdx.x * 256 + threadIdx.x) * 8;  // total = 25088*512
  float4_t a = *(const float4_t*)&in[i];
  float4_t b = *(const float4_t*)&in[i + 4];
  short8 v;
  v[0] = f2bf(a[0]); v[1] = f2bf(a[1]); v[2] = f2bf(a[2]); v[3] = f2bf(a[3]);
  v[4] = f2bf(b[0]); v[5] = f2bf(b[1]); v[6] = f2bf(b[2]); v[7] = f2bf(b[3]);
  *(short8*)&out[i] = v;
}

// ------------- weight transpose+cvt: out_bf16[C][R] = in_f32[R][C] -----------
__global__ __launch_bounds__(256) void transpose_kernel(
    const float* __restrict__ in, short* __restrict__ out, int R, int C) {
  __shared__ float tile[64][65];
  int c0 = blockIdx.x * 64, r0 = blockIdx.y * 64;
  int tc = threadIdx.x & 63, tr = threadIdx.x >> 6;
#pragma unroll
  for (int s = 0; s < 16; s++) {
    int r = s * 4 + tr;
    tile[r][tc] = in[(r0 + r) * C + c0 + tc];
  }
  __syncthreads();
#pragma unroll
  for (int s = 0; s < 16; s++) {
    int i = s * 4 + tr;
    out[(c0 + i) * R + r0 + tc] = f2bf(tile[tc][i]);
  }
}

// ---------------- bias precompute: bias[h][q<208][k<208] fp32 ----------------
__global__ __launch_bounds__(256) void bias_kernel(
    const float* __restrict__ table, const int* __restrict__ rpi,
    float* __restrict__ bias) {
  int idx = blockIdx.x * 256 + threadIdx.x;
  if (idx >= 16 * QPAD * KP) return;
  int h = idx / (QPAD * KP);
  int rem = idx % (QPAD * KP);
  int q = rem / KP, k = rem % KP;
  float v = 0.f;
  if (q < NTOK && k < NTOK) v = table[rpi[q * NTOK + k] * 16 + h];
  bias[idx] = v;
}

// ---------------- shared 128x128 GEMM mainloop (validated) ----------------
__device__ __forceinline__ void gemm_tile(const short* __restrict__ A,
                                          const short* __restrict__ B, int K,
                                          int m0, int n0, short (*As)[72],
                                          short (*Bs)[72], float4_t acc[4][4]) {
  int tid = threadIdx.x;
  int lane = tid & 63, wave = tid >> 6;
  int quad = lane >> 4, l16 = lane & 15;
  int wm = (wave >> 1) * 64, wn = (wave & 1) * 64;
  int srow = tid >> 3, scol = (tid & 7) * 8;
  for (int k0 = 0; k0 < K; k0 += 64) {
#pragma unroll
    for (int i = 0; i < 4; i++) {
      int r = srow + i * 32;
      *(short8*)&As[r][scol] = *(const short8*)&A[(m0 + r) * K + k0 + scol];
      *(short8*)&Bs[r][scol] = *(const short8*)&B[(n0 + r) * K + k0 + scol];
    }
    __syncthreads();
#pragma unroll
    for (int ks = 0; ks < 2; ks++) {
      short8 af[4], bfr[4];
#pragma unroll
      for (int i = 0; i < 4; i++) {
        af[i] = *(short8*)&As[wm + i * 16 + l16][ks * 32 + quad * 8];
        bfr[i] = *(short8*)&Bs[wn + i * 16 + l16][ks * 32 + quad * 8];
      }
#pragma unroll
      for (int mi = 0; mi < 4; mi++)
#pragma unroll
        for (int ni = 0; ni < 4; ni++)
          acc[mi][ni] = __builtin_amdgcn_mfma_f32_16x16x32_bf16(
              af[mi], bfr[ni], acc[mi][ni], 0, 0, 0);
    }
    __syncthreads();
  }
}

// -------- split path: QKV GEMM with scatter epilogue into q/k/v slabs --------
__global__ __launch_bounds__(256) void qkv_gemm(
    const short* __restrict__ xb, const short* __restrict__ wt1,
    short* __restrict__ qb, short* __restrict__ kb, short* __restrict__ vb) {
  __shared__ __align__(16) short As[128][72];
  __shared__ __align__(16) short Bs[128][72];
  float4_t acc[4][4];
  float4_t z = {0.f, 0.f, 0.f, 0.f};
#pragma unroll
  for (int i = 0; i < 4; i++)
#pragma unroll
    for (int j = 0; j < 4; j++) acc[i][j] = z;
  int m0 = blockIdx.y * 128, n0 = blockIdx.x * 128;
  gemm_tile(xb, wt1, 512, m0, n0, As, Bs, acc);
  int lane = threadIdx.x & 63, wave = threadIdx.x >> 6;
  int quad = lane >> 4, l16 = lane & 15;
  int wm = (wave >> 1) * 64, wn = (wave & 1) * 64;
  const float qscale = 0.17677669529663687f;  // 32^-0.5
#pragma unroll
  for (int mi = 0; mi < 4; mi++)
#pragma unroll
    for (int ni = 0; ni < 4; ni++)
#pragma unroll
      for (int r = 0; r < 4; r++) {
        int rowg = m0 + wm + mi * 16 + quad * 4 + r;
        int colg = n0 + wn + ni * 16 + l16;
        float v = acc[mi][ni][r];
        int s = colg >> 9, rem = colg & 511;
        int h = rem >> 5, d = rem & 31;
        int b = rowg / NTOK, n = rowg - b * NTOK;
        int off = ((b * 16 + h) * QPAD + n) * 32 + d;
        if (s == 0)
          qb[off] = f2bf(v * qscale);
        else if (s == 1)
          kb[off] = f2bf(v);
        else
          vb[off] = f2bf(v);
      }
}

// -------- split path: attention, one block per (b,h), 3 blocks/CU --------
__global__ __launch_bounds__(256) void attn_kernel(
    const short* __restrict__ qb, const short* __restrict__ kb,
    const short* __restrict__ vb, const float* __restrict__ bias,
    short* __restrict__ aout) {
  __shared__ __align__(16) short vT[32][PSTR];
  __shared__ __align__(16) short P[4][16][PSTR];
  int bh = blockIdx.x, b = bh >> 4, h = bh & 15;
  int tid = threadIdx.x, wave = tid >> 6, lane = tid & 63;
  int quad = lane >> 4, l16 = lane & 15;
  int base_row = b * NTOK;
  // stage V transposed (keys 0..195); zero pad keys 196..231
  const short* vsrc = vb + bh * QPAD * 32;
  for (int i = tid; i < NTOK * 32; i += 256) {
    int key = i >> 5, d = i & 31;
    vT[d][key] = vsrc[i];
  }
  for (int i = tid; i < 32 * (PSTR - NTOK); i += 256) {
    int d = i / (PSTR - NTOK), c = i - d * (PSTR - NTOK);
    vT[d][NTOK + c] = 0;
  }
  __syncthreads();
  float4_t z4 = {0.f, 0.f, 0.f, 0.f};
  for (int i2 = 0; i2 < 4; i2++) {
    bool active = (i2 < 3) || (wave == 0);
    int qt = (i2 < 3) ? (wave + 4 * i2) : 12;
    int qr0 = qt * 16;
    if (active) {
      short8 qf = *(const short8*)&qb[(bh * QPAD + qr0 + l16) * 32 + quad * 8];
      float4_t s[13];
#pragma unroll
      for (int kt = 0; kt < 13; kt++) {
        short8 kf =
            *(const short8*)&kb[(bh * QPAD + kt * 16 + l16) * 32 + quad * 8];
        s[kt] = __builtin_amdgcn_mfma_f32_16x16x32_bf16(qf, kf, z4, 0, 0, 0);
      }
      const float* brow = bias + (h * QPAD + qr0 + quad * 4) * KP;
#pragma unroll
      for (int kt = 0; kt < 13; kt++) {
        int col = kt * 16 + l16;
#pragma unroll
        for (int r = 0; r < 4; r++) s[kt][r] += brow[r * KP + col];
      }
      if (l16 >= 4) {
#pragma unroll
        for (int r = 0; r < 4; r++) s[12][r] = -1e30f;  // mask pad keys
      }
#pragma unroll
      for (int r = 0; r < 4; r++) {
        float m = s[0][r];
#pragma unroll
        for (int kt = 1; kt < 13; kt++) m = fmaxf(m, s[kt][r]);
        m = fmaxf(m, __shfl_xor(m, 8, 16));
        m = fmaxf(m, __shfl_xor(m, 4, 16));
        m = fmaxf(m, __shfl_xor(m, 2, 16));
        m = fmaxf(m, __shfl_xor(m, 1, 16));
        float sum = 0.f;
#pragma unroll
        for (int kt = 0; kt < 13; kt++) {
          float p = __expf(s[kt][r] - m);
          s[kt][r] = p;
          sum += p;
        }
        sum += __shfl_xor(sum, 8, 16);
        sum += __shfl_xor(sum, 4, 16);
        sum += __shfl_xor(sum, 2, 16);
        sum += __shfl_xor(sum, 1, 16);
        float inv = 1.f / sum;
        short* prow = &P[wave][quad * 4 + r][0];
#pragma unroll
        for (int kt = 0; kt < 13; kt++)
          prow[kt * 16 + l16] = f2bf(s[kt][r] * inv);
        prow[208 + l16] = 0;  // zero pad cols 208..223 (224.. never read)
      }
    }
    __syncthreads();  // P writes visible before fragment reads
    if (active) {
      float4_t o0 = z4, o1 = z4;
#pragma unroll
      for (int kt = 0; kt < 7; kt++) {
        short8 pf = *(short8*)&P[wave][l16][kt * 32 + quad * 8];
        short8 vf0 = *(short8*)&vT[l16][kt * 32 + quad * 8];
        short8 vf1 = *(short8*)&vT[16 + l16][kt * 32 + quad * 8];
        o0 = __builtin_amdgcn_mfma_f32_16x16x32_bf16(pf, vf0, o0, 0, 0, 0);
        o1 = __builtin_amdgcn_mfma_f32_16x16x32_bf16(pf, vf1, o1, 0, 0, 0);
      }
#pragma unroll
      for (int r = 0; r < 4; r++) {
        int row = qr0 + quad * 4 + r;
        if (row < NTOK) {
          int off = (base_row + row) * 512 + h * 32;
          aout[off + l16] = f2bf(o0[r]);
          aout[off + 16 + l16] = f2bf(o1[r]);
        }
      }
    }
    __syncthreads();  // protect P slab before next iteration overwrite
  }
}

// ---------------- fallback fused QKV-GEMM + attention (round-4, validated) ---
__global__ __launch_bounds__(256, 2) void fused_attn(
    const short* __restrict__ xb, const short* __restrict__ wt1,
    const float* __restrict__ bias, short* __restrict__ aout) {
  __shared__ __align__(16) short R1[64 * PSTR];
  __shared__ __align__(16) short R2[32 * PSTR];
  __shared__ __align__(16) short Qs[224][40];
  __shared__ __align__(16) short Ks[224][40];
  short(*As)[40] = (short(*)[40])R1;
  short(*P)[PSTR] = (short(*)[PSTR])R1;
  short(*Bs)[40] = (short(*)[40])R2;
  short(*vTs)[PSTR] = (short(*)[PSTR])R2;

  int bh = blockIdx.x, b = bh >> 4, h = bh & 15;
  int tid = threadIdx.x, wave = tid >> 6, lane = tid & 63;
  int quad = lane >> 4, l16 = lane & 15;
  int base_row = b * NTOK;

  float4_t z4 = {0.f, 0.f, 0.f, 0.f};
  float4_t acc[4][6];
#pragma unroll
  for (int i = 0; i < 4; i++)
#pragma unroll
    for (int n = 0; n < 6; n++) acc[i][n] = z4;

  int srow = tid >> 2, scol = (tid & 3) * 8;
  for (int k0 = 0; k0 < 512; k0 += 32) {
#pragma unroll
    for (int i = 0; i < 4; i++) {
      int r = srow + i * 64;
      if (r < 224) {
        int gr = base_row + r;
        if (gr > 25087) gr = 25087;
        *(short8*)&As[r][scol] = *(const short8*)&xb[gr * 512 + k0 + scol];
      }
    }
#pragma unroll
    for (int i = 0; i < 2; i++) {
      int r = srow + i * 64;
      if (r < 96) {
        int sec = r >> 5, r32 = r & 31;
        *(short8*)&Bs[r][scol] =
            *(const short8*)&wt1[(sec * 512 + h * 32 + r32) * 512 + k0 + scol];
      }
    }
    __syncthreads();
    short8 af[4], bfv[6];
#pragma unroll
    for (int i = 0; i < 4; i++) {
      int mt = (i < 3) ? (wave + 4 * i) : (12 + (wave & 1));
      af[i] = *(short8*)&As[mt * 16 + l16][quad * 8];
    }
#pragma unroll
    for (int n = 0; n < 6; n++) bfv[n] = *(short8*)&Bs[n * 16 + l16][quad * 8];
#pragma unroll
    for (int i = 0; i < 4; i++)
#pragma unroll
      for (int n = 0; n < 6; n++)
        acc[i][n] = __builtin_amdgcn_mfma_f32_16x16x32_bf16(af[i], bfv[n],
                                                            acc[i][n], 0, 0, 0);
    __syncthreads();
  }
  const float qscale = 0.17677669529663687f;
#pragma unroll
  for (int i = 0; i < 4; i++) {
    if (i == 3 && wave >= 2) break;
    int mt = (i < 3) ? (wave + 4 * i) : (12 + wave);
    int row0 = mt * 16 + quad * 4;
#pragma unroll
    for (int n = 0; n < 6; n++) {
      int c = n * 16 + l16;
#pragma unroll
      for (int r = 0; r < 4; r++) {
        int row = row0 + r;
        float v = acc[i][n][r];
        if (c < 32)
          Qs[row][c] = f2bf(v * qscale);
        else if (c < 64)
          Ks[row][c - 32] = f2bf(v);
        else
          vTs[c - 64][row] = f2bf(v);
      }
    }
  }
  __syncthreads();
  for (int i2 = 0; i2 < 4; i2++) {
    bool active = (i2 < 3) || (wave == 0);
    int qt = (i2 < 3) ? (wave + 4 * i2) : 12;
    int qr0 = qt * 16;
    if (active) {
      short8 qf = *(short8*)&Qs[qr0 + l16][quad * 8];
      float4_t s[13];
#pragma unroll
      for (int kt = 0; kt < 13; kt++) {
        short8 kf = *(short8*)&Ks[kt * 16 + l16][quad * 8];
        s[kt] = __builtin_amdgcn_mfma_f32_16x16x32_bf16(qf, kf, z4, 0, 0, 0);
      }
      const float* brow = bias + (h * QPAD + qr0 + quad * 4) * KP;
#pragma unroll
      for (int kt = 0; kt < 13; kt++) {
        int col = kt * 16 + l16;
#pragma unroll
        for (int r = 0; r < 4; r++) s[kt][r] += brow[r * KP + col];
      }
      if (l16 >= 4) {
#pragma unroll
        for (int r = 0; r < 4; r++) s[12][r] = -1e30f;
      }
      int prow_base = wave * 16 + quad * 4;
#pragma unroll
      for (int r = 0; r < 4; r++) {
        float m = s[0][r];
#pragma unroll
        for (int kt = 1; kt < 13; kt++) m = fmaxf(m, s[kt][r]);
        m = fmaxf(m, __shfl_xor(m, 8, 16));
        m = fmaxf(m, __shfl_xor(m, 4, 16));
        m = fmaxf(m, __shfl_xor(m, 2, 16));
        m = fmaxf(m, __shfl_xor(m, 1, 16));
        float sum = 0.f;
#pragma unroll
        for (int kt = 0; kt < 13; kt++) {
          float p = __expf(s[kt][r] - m);
          s[kt][r] = p;
          sum += p;
        }
        sum += __shfl_xor(sum, 8, 16);
        sum += __shfl_xor(sum, 4, 16);
        sum += __shfl_xor(sum, 2, 16);
        sum += __shfl_xor(sum, 1, 16);
        float inv = 1.f / sum;
        short* prow = &P[prow_base + r][0];
#pragma unroll
        for (int kt = 0; kt < 13; kt++)
          prow[kt * 16 + l16] = f2bf(s[kt][r] * inv);
        prow[208 + l16] = 0;
      }
    }
    __syncthreads();
    if (active) {
      float4_t o0 = z4, o1 = z4;
#pragma unroll
      for (int kt = 0; kt < 7; kt++) {
        short8 pf = *(short8*)&P[wave * 16 + l16][kt * 32 + quad * 8];
        short8 vf0 = *(short8*)&vTs[l16][kt * 32 + quad * 8];
        short8 vf1 = *(short8*)&vTs[16 + l16][kt * 32 + quad * 8];
        o0 = __builtin_amdgcn_mfma_f32_16x16x32_bf16(pf, vf0, o0, 0, 0, 0);
        o1 = __builtin_amdgcn_mfma_f32_16x16x32_bf16(pf, vf1, o1, 0, 0, 0);
      }
#pragma unroll
      for (int r = 0; r < 4; r++) {
        int row = qr0 + quad * 4 + r;
        if (row < NTOK) {
          int off = (base_row + row) * 512 + h * 32;
          aout[off + l16] = f2bf(o0[r]);
          aout[off + 16 + l16] = f2bf(o1[r]);
        }
      }
    }
    __syncthreads();
  }
}

// ------------- proj GEMM + bias: out_f32 = aout[25088,512] @ w2^T + b --------
__global__ __launch_bounds__(256) void proj_gemm(
    const short* __restrict__ a, const short* __restrict__ wt,
    const float* __restrict__ pb, float* __restrict__ out) {
  __shared__ __align__(16) short As[128][72];
  __shared__ __align__(16) short Bs[128][72];
  float4_t acc[4][4];
  float4_t z = {0.f, 0.f, 0.f, 0.f};
#pragma unroll
  for (int i = 0; i < 4; i++)
#pragma unroll
    for (int j = 0; j < 4; j++) acc[i][j] = z;
  int m0 = blockIdx.y * 128, n0 = blockIdx.x * 128;
  gemm_tile(a, wt, 512, m0, n0, As, Bs, acc);
  int lane = threadIdx.x & 63, wave = threadIdx.x >> 6;
  int quad = lane >> 4, l16 = lane & 15;
  int wm = (wave >> 1) * 64, wn = (wave & 1) * 64;
#pragma unroll
  for (int mi = 0; mi < 4; mi++)
#pragma unroll
    for (int ni = 0; ni < 4; ni++) {
      int colg = n0 + wn + ni * 16 + l16;
      float bv = pb[colg];
#pragma unroll
      for (int r = 0; r < 4; r++) {
        int rowg = m0 + wm + mi * 16 + quad * 4 + r;
        out[rowg * 512 + colg] = acc[mi][ni][r] + bv;
      }
    }
}

extern "C" void kernel_launch(void* const* d_in, const int* in_sizes, int n_in,
                              void* d_out, int out_size, void* d_ws,
                              size_t ws_size, hipStream_t stream) {
  const float* x = (const float*)d_in[0];       // [25088,512] fp32
  const float* qkv_w = (const float*)d_in[1];   // [512,1536] fp32
  const float* table = (const float*)d_in[2];   // [729,16] fp32
  const float* proj_w = (const float*)d_in[3];  // [512,512] fp32
  const float* proj_b = (const float*)d_in[4];  // [512] fp32
  const int* rpi = (const int*)d_in[5];         // [196,196] int32
  float* out = (float*)d_out;

  char* w = (char*)d_ws;
  short* wt1 = (short*)(w);              // 1536*512*2   = 1,572,864
  short* wt2 = (short*)(w + 1572864);    // 512*512*2    =   524,288
  float* bias = (float*)(w + 2097152);   // 16*208*208*4 = 2,768,896
  short* xb = (short*)(w + 4866048);     // 25088*512*2  = 25,690,112
  // split-path extra slabs (q,k,v) on top:
  short* qb = (short*)(w + 30556160);    // 2048*208*32*2 = 27,262,976
  short* kb = (short*)(w + 57819136);
  short* vb = (short*)(w + 85082112);
  const size_t NEEDED_SPLIT = 112345088;
  const size_t NEEDED_FUSED = 30556160 + 25690112;  // fused path slabs

  transpose_kernel<<<dim3(24, 8), 256, 0, stream>>>(qkv_w, wt1, 512, 1536);
  transpose_kernel<<<dim3(8, 8), 256, 0, stream>>>(proj_w, wt2, 512, 512);
  bias_kernel<<<(16 * QPAD * KP + 255) / 256, 256, 0, stream>>>(table, rpi,
                                                                bias);
  if (ws_size >= NEEDED_SPLIT) {
    // split path: xb slab doubles as aout (xb dead after qkv_gemm)
    short* aout = xb;
    cvt_kernel<<<25088 * 512 / (256 * 8), 256, 0, stream>>>(x, xb);
    qkv_gemm<<<dim3(12, 196), 256, 0, stream>>>(xb, wt1, qb, kb, vb);
    attn_kernel<<<2048, 256, 0, stream>>>(qb, kb, vb, bias, aout);
    proj_gemm<<<dim3(4, 196), 256, 0, stream>>>(aout, wt2, proj_b, out);
  } else if (ws_size >= NEEDED_FUSED) {
    short* aout = (short*)(w + 30556160);  // separate slab, round-4 layout
    cvt_kernel<<<25088 * 512 / (256 * 8), 256, 0, stream>>>(x, xb);
    fused_attn<<<2048, 256, 0, stream>>>(xb, wt1, bias, aout);
    proj_gemm<<<dim3(4, 196), 256, 0, stream>>>(aout, wt2, proj_b, out);
  } else {
    fill_kernel<<<(out_size + 255) / 256, 256, 0, stream>>>(out, out_size);
  }
}